// Round 11
// baseline (200.162 us; speedup 1.0000x reference)
//
#include <hip/hip_runtime.h>
#include <cmath>

// MultimodalCrossAttention on MI355X (gfx950), bf16 MFMA pipeline.
// B=2, Sx=Sc=2048, D_MODEL=1024, H=16, hd=64.

typedef __bf16 bf16x8 __attribute__((ext_vector_type(8)));
typedef __bf16 bf16x4 __attribute__((ext_vector_type(4)));
typedef float f32x4 __attribute__((ext_vector_type(4)));
typedef float f32x16 __attribute__((ext_vector_type(16)));
typedef unsigned u32x4v __attribute__((ext_vector_type(4)));

#define MFMA(A, B, C) __builtin_amdgcn_mfma_f32_16x16x32_bf16(A, B, C, 0, 0, 0)
#define MFMA32(A, B, C) __builtin_amdgcn_mfma_f32_32x32x16_bf16(A, B, C, 0, 0, 0)
#define GLL16(g, l)                                                        \
  __builtin_amdgcn_global_load_lds(                                        \
      (const __attribute__((address_space(1))) unsigned int*)(g),          \
      (__attribute__((address_space(3))) unsigned int*)(l), 16, 0, 0)

#define VMCNT(N) asm volatile("s_waitcnt vmcnt(" #N ")" ::: "memory")
#define BARM() asm volatile("s_barrier" ::: "memory")
#define LGKM0() asm volatile("s_waitcnt lgkmcnt(0)" ::: "memory")

// ---------------- fused fp32 -> bf16 convert, 2 float4/thread ----------------
__global__ __launch_bounds__(256) void cvt_all_kernel(
    const float* __restrict__ x, const float* __restrict__ ctx,
    const float* __restrict__ Wq, const float* __restrict__ Wv,
    const float* __restrict__ Wo, __bf16* __restrict__ xb, __bf16* __restrict__ cb,
    __bf16* __restrict__ Wqb, __bf16* __restrict__ Wvb, __bf16* __restrict__ Wob) {
  int base = blockIdx.x * 512 + threadIdx.x;
  const float* src;
  __bf16* dst;
  int off;
  if (base < 1048576) { src = x; dst = xb; off = 0; }
  else if (base < 2097152) { src = ctx; dst = cb; off = 1048576; }
  else if (base < 2359296) { src = Wq; dst = Wqb; off = 2097152; }
  else if (base < 2621440) { src = Wv; dst = Wvb; off = 2359296; }
  else { src = Wo; dst = Wob; off = 2621440; }
#pragma unroll
  for (int jj = 0; jj < 2; jj++) {
    int j = base - off + jj * 256;
    float4 f = ((const float4*)src)[j];
    bf16x4 o;
    o[0] = (__bf16)f.x; o[1] = (__bf16)f.y; o[2] = (__bf16)f.z; o[3] = (__bf16)f.w;
    ((bf16x4*)dst)[j] = o;
  }
}

// ---------------- Projection GEMM: 256x256, 8-phase schedule (proven round 6) ----------------
// K epilogue now writes K'' chunk layout [bh][s/32][d/8][32][8]
// (elem (s,d) at ((s>>5)*8+(d>>3))*256 + (s&31)*8 + (d&7)), V'' as round 10,
// so attn streams BOTH operands global->reg with 16B/lane coalesced loads.
__global__ __launch_bounds__(512, 2) void gemm_proj(const __bf16* __restrict__ A0,
                                                    const __bf16* __restrict__ W0,
                                                    void* __restrict__ outQ,
                                                    void* __restrict__ outK,
                                                    void* __restrict__ outV) {
  const int tid = threadIdx.x;
  const int wave = tid >> 6, lane = tid & 63, quad = lane >> 4, l15 = lane & 15;
  const int wm = wave >> 2, wn = wave & 3;

  const int id = blockIdx.x;
  int m0, n0;
  const __bf16* A;
  const __bf16* W;
  bool vmode;
  if (id < 128) {                        // QK: A = xb||cb (8192 rows), W = Wq
    const int xcd = id & 7, j = id >> 3; // j 0..15
    m0 = (xcd * 4 + (j & 3)) * 256;
    n0 = (j >> 2) * 256;
    A = A0;
    W = W0;
    vmode = false;
  } else {                               // V: A = cb (4096 rows), W = Wv
    const int vid = id - 128;
    const int xcd = vid & 7, j = vid >> 3;  // j 0..7
    m0 = (xcd * 2 + (j & 1)) * 256;
    n0 = (j >> 1) * 256;
    A = A0 + (size_t)4096 * 1024;
    W = W0 + (size_t)1024 * 1024;
    vmode = true;
  }

  __shared__ __attribute__((aligned(16))) __bf16 As[2][2][8192];  // 64KB
  __shared__ __attribute__((aligned(16))) __bf16 Bs[2][2][8192];  // 64KB

  const int srow = tid >> 2;
  const int kcg = (tid & 3) ^ (srow & 3);
  const size_t aoff0 = (size_t)srow * 1024 + kcg * 8;
  const size_t aoff1 = (size_t)(srow + 128) * 1024 + kcg * 8;
  const __bf16* Ag = A + (size_t)m0 * 1024;
  const __bf16* Wg = W + (size_t)n0 * 1024;
  const int ldst0 = wave * 512;
  const int ldst1 = 4096 + wave * 512;

  auto stageA = [&](int slot, int kh, int kel) {
    GLL16(Ag + aoff0 + kel, &As[slot][kh][ldst0]);
    GLL16(Ag + aoff1 + kel, &As[slot][kh][ldst1]);
  };
  auto stageB = [&](int slot, int kh, int kel) {
    GLL16(Wg + aoff0 + kel, &Bs[slot][kh][ldst0]);
    GLL16(Wg + aoff1 + kel, &Bs[slot][kh][ldst1]);
  };

  const int xk = (quad ^ (l15 & 3)) * 8;
  int afo[8], bfo[4];
#pragma unroll
  for (int mf = 0; mf < 8; mf++) afo[mf] = (wm * 128 + mf * 16 + l15) * 32 + xk;
#pragma unroll
  for (int nf = 0; nf < 4; nf++) bfo[nf] = (wn * 64 + nf * 16 + l15) * 32 + xk;

  f32x4 acc[8][4] = {};
  bf16x8 bf[4], af[4];

  auto loadB = [&](int slot, int kh) {
#pragma unroll
    for (int nf = 0; nf < 4; nf++) bf[nf] = *(const bf16x8*)&Bs[slot][kh][bfo[nf]];
  };
  auto loadA = [&](int slot, int kh, int mfg) {
#pragma unroll
    for (int mf = 0; mf < 4; mf++)
      af[mf] = *(const bf16x8*)&As[slot][kh][afo[mfg * 4 + mf]];
  };
  auto mfma16 = [&](int mfg) {
    __builtin_amdgcn_s_setprio(1);
#pragma unroll
    for (int mf = 0; mf < 4; mf++)
#pragma unroll
      for (int nf = 0; nf < 4; nf++)
        acc[mfg * 4 + mf][nf] = MFMA(af[mf], bf[nf], acc[mfg * 4 + mf][nf]);
    __builtin_amdgcn_s_setprio(0);
  };

  stageA(0, 0, 0);  stageB(0, 0, 0);
  stageA(0, 1, 32); stageB(0, 1, 32);
  stageA(1, 0, 64); stageB(1, 0, 64);
  VMCNT(8); BARM();

#pragma unroll 1
  for (int j = 0; j < 7; j++) {
    const int kb = j * 128;
    loadB(0, 0); loadA(0, 0, 0); stageA(1, 1, kb + 96);
    BARM(); LGKM0(); mfma16(0); BARM();
    loadA(0, 0, 1); stageB(1, 1, kb + 96);
    BARM(); LGKM0(); mfma16(1); VMCNT(8); BARM();
    loadB(0, 1); loadA(0, 1, 0); stageA(0, 0, kb + 128);
    BARM(); LGKM0(); mfma16(0); BARM();
    loadA(0, 1, 1); stageB(0, 0, kb + 128);
    BARM(); LGKM0(); mfma16(1); VMCNT(8); BARM();
    loadB(1, 0); loadA(1, 0, 0); stageA(0, 1, kb + 160);
    BARM(); LGKM0(); mfma16(0); BARM();
    loadA(1, 0, 1); stageB(0, 1, kb + 160);
    BARM(); LGKM0(); mfma16(1); VMCNT(8); BARM();
    loadB(1, 1); loadA(1, 1, 0); stageA(1, 0, kb + 192);
    BARM(); LGKM0(); mfma16(0); BARM();
    loadA(1, 1, 1); stageB(1, 0, kb + 192);
    BARM(); LGKM0(); mfma16(1); VMCNT(8); BARM();
  }
  {
    loadB(0, 0); loadA(0, 0, 0); stageA(1, 1, 992);
    BARM(); LGKM0(); mfma16(0); BARM();
    loadA(0, 0, 1); stageB(1, 1, 992);
    BARM(); LGKM0(); mfma16(1); VMCNT(8); BARM();
    loadB(0, 1); loadA(0, 1, 0);
    BARM(); LGKM0(); mfma16(0); BARM();
    loadA(0, 1, 1);
    BARM(); LGKM0(); mfma16(1); VMCNT(4); BARM();
    loadB(1, 0); loadA(1, 0, 0);
    BARM(); LGKM0(); mfma16(0); BARM();
    loadA(1, 0, 1);
    BARM(); LGKM0(); mfma16(1); VMCNT(0); BARM();
    loadB(1, 1); loadA(1, 1, 0);
    BARM(); LGKM0(); mfma16(0); BARM();
    loadA(1, 1, 1);
    BARM(); LGKM0(); mfma16(1);
  }

  if (!vmode) {
    const int isK = (m0 >= 4096);
    __bf16* O = (__bf16*)(isK ? outK : outQ);
    const float qsc = isK ? 1.0f : 0.18033688f;  // 0.125*log2(e) folded into Q
    const int mb = m0 & 4095;
    if (!isK) {
      // Q: row-major [b,h,s,d]
#pragma unroll
      for (int nf = 0; nf < 4; nf++) {
        const int n = n0 + wn * 64 + nf * 16 + l15;
        const int h = n >> 6, d = n & 63, p = d >> 1;
        const float invf_rev =
            __builtin_amdgcn_exp2f(-((float)p * 0.41524101f + 2.6514961f));
#pragma unroll
        for (int mf = 0; mf < 8; mf++) {
#pragma unroll
          for (int r = 0; r < 4; r++) {
            const int row = mb + wm * 128 + mf * 16 + quad * 4 + r;
            const int s = row & 2047, b = row >> 11;
            float v = acc[mf][nf][r];
            float pv = __shfl_xor(v, 1, 64);
            float fr = __builtin_amdgcn_fractf((float)s * invf_rev);
            float sn = __builtin_amdgcn_sinf(fr);
            float cs = __builtin_amdgcn_cosf(fr);
            float res = (lane & 1) ? (pv * sn + v * cs) : (v * cs - pv * sn);
            O[((size_t)(b * 16 + h) * 2048 + s) * 64 + d] = (__bf16)(res * qsc);
          }
        }
      }
    } else {
      // K'': chunk layout, elem (s,d) at ((s>>5)*8+(d>>3))*256 + (s&31)*8 + (d&7)
#pragma unroll
      for (int nf = 0; nf < 4; nf++) {
        const int n = n0 + wn * 64 + nf * 16 + l15;
        const int h = n >> 6, d = n & 63, p = d >> 1;
        const float invf_rev =
            __builtin_amdgcn_exp2f(-((float)p * 0.41524101f + 2.6514961f));
#pragma unroll
        for (int mf = 0; mf < 8; mf++) {
#pragma unroll
          for (int r = 0; r < 4; r++) {
            const int row = mb + wm * 128 + mf * 16 + quad * 4 + r;
            const int s = row & 2047, b = row >> 11;
            float v = acc[mf][nf][r];
            float pv = __shfl_xor(v, 1, 64);
            float fr = __builtin_amdgcn_fractf((float)s * invf_rev);
            float sn = __builtin_amdgcn_sinf(fr);
            float cs = __builtin_amdgcn_cosf(fr);
            float res = (lane & 1) ? (pv * sn + v * cs) : (v * cs - pv * sn);
            O[(size_t)(b * 16 + h) * 131072 +
              (size_t)((s >> 5) * 8 + (d >> 3)) * 256 + (s & 31) * 8 + (d & 7)] =
                (__bf16)res;
          }
        }
      }
    }
  } else {
    // V'' chunk layout: plane = (b*16+h)*131072; elem (s,d) at (s>>3)*512 + d*8 + (s&7)
    __bf16* O = (__bf16*)outV;
#pragma unroll
    for (int nf = 0; nf < 4; nf++) {
      const int n = n0 + wn * 64 + nf * 16 + l15;
      const int h = n >> 6, d = n & 63;
#pragma unroll
      for (int mf = 0; mf < 8; mf++) {
        const int rowb = m0 + wm * 128 + mf * 16 + quad * 4;
        const int s = rowb & 2047, b = rowb >> 11;
        bf16x4 o;
#pragma unroll
        for (int r = 0; r < 4; r++) o[r] = (__bf16)acc[mf][nf][r];
        *(bf16x4*)(O + (size_t)(b * 16 + h) * 131072 + (size_t)(s >> 3) * 512 +
                   d * 8 + (s & 7)) = o;
      }
    }
  }
}

// ---------------- Out-proj GEMM: 128x64 tile, triple-buffered, XCD-swizzled ----------------
// (round-2 proven version)
__global__ __launch_bounds__(256) void gemm_out(const __bf16* __restrict__ A,
                                                const __bf16* __restrict__ W,
                                                float* __restrict__ O,
                                                const float* __restrict__ bias) {
  const int tid = threadIdx.x;
  const int wave = tid >> 6, lane = tid & 63, quad = lane >> 4, l15 = lane & 15;
  const int mw = wave >> 1, nw = wave & 1;
  const int id = blockIdx.x;
  const int xcd = id & 7, j = id >> 3;       // j 0..63
  const int m0 = (xcd * 4 + (j & 3)) * 128;  // 32 m-tiles
  const int n0 = (j >> 2) * 64;              // 16 n-tiles

  __shared__ __attribute__((aligned(16))) __bf16 As[3][4096];  // 24KB
  __shared__ __attribute__((aligned(16))) __bf16 Ws[3][2048];  // 12KB

  int goff[2];
#pragma unroll
  for (int jj = 0; jj < 2; jj++) {
    const int s = jj * 256 + tid;
    const int row = s >> 2;
    const int kcg = (s & 3) ^ ((row >> 1) & 3);
    goff[jj] = row * 1024 + kcg * 8;
  }
  const int wrow = tid >> 2;
  const int wkcg = (tid & 3) ^ ((wrow >> 1) & 3);
  const int goffw = wrow * 1024 + wkcg * 8;

  const __bf16* Ag = A + (size_t)m0 * 1024;
  const __bf16* Wg = W + (size_t)n0 * 1024;
  const int ldsoff0 = wave * 512;
  const int ldsoff1 = 2048 + wave * 512;

  const int sw = (l15 >> 1) & 3;
  int afoff[4], wfoff[2];
#pragma unroll
  for (int t = 0; t < 4; t++)
    afoff[t] = (mw * 64 + t * 16 + l15) * 32 + (quad ^ sw) * 8;
#pragma unroll
  for (int t = 0; t < 2; t++)
    wfoff[t] = (nw * 32 + t * 16 + l15) * 32 + (quad ^ sw) * 8;

  f32x4 acc[4][2] = {};

  auto stage = [&](int buf, int k0) {
    GLL16(Ag + goff[0] + k0, &As[buf][ldsoff0]);
    GLL16(Ag + goff[1] + k0, &As[buf][ldsoff1]);
    GLL16(Wg + goffw + k0, &Ws[buf][ldsoff0]);
  };
  auto compute = [&](int buf) {
    bf16x8 af[4], wf[2];
#pragma unroll
    for (int t = 0; t < 4; t++) af[t] = *(const bf16x8*)&As[buf][afoff[t]];
#pragma unroll
    for (int t = 0; t < 2; t++) wf[t] = *(const bf16x8*)&Ws[buf][wfoff[t]];
#pragma unroll
    for (int mt = 0; mt < 4; mt++)
#pragma unroll
      for (int nt = 0; nt < 2; nt++) acc[mt][nt] = MFMA(af[mt], wf[nt], acc[mt][nt]);
  };

  stage(0, 0);
  stage(1, 32);
  int buf = 0;
  for (int c = 0; c < 32; c++) {
    __syncthreads();
    if (c + 2 < 32) {
      int nb = buf + 2;
      if (nb >= 3) nb -= 3;
      stage(nb, (c + 2) * 32);
    }
    compute(buf);
    buf = (buf == 2) ? 0 : buf + 1;
  }

#pragma unroll
  for (int nt = 0; nt < 2; nt++) {
    const int n = n0 + nw * 32 + nt * 16 + l15;
    const float bv = bias[n];
#pragma unroll
    for (int mt = 0; mt < 4; mt++) {
#pragma unroll
      for (int r = 0; r < 4; r++) {
        const int row = m0 + mw * 64 + mt * 16 + quad * 4 + r;
        O[(size_t)row * 1024 + n] = acc[mt][nt][r] + bv;
      }
    }
  }
}

// ---------------- Flash attention: barrier-free, K & V streamed global->reg ----------------
// No LDS, no barriers in the main loop: each wave streams its K''/V'' fragments
// (16B/lane coalesced; 4-qg fan-out served by L1, per-tile set 16KB < 32KB L1)
// 2-deep ping-pong (named reg sets, rule #20). LDS only for the epilogue
// cross-kg reduction (34KB). Waves drift freely -> pipes overlap.
__global__ __launch_bounds__(512, 2) void attn_kernel(const __bf16* __restrict__ Q,
                                                      const __bf16* __restrict__ K,
                                                      const __bf16* __restrict__ Vt,
                                                      __bf16* __restrict__ Aout) {
  const int tid = threadIdx.x;
  const int wave = tid >> 6, lane = tid & 63;
  const int l31 = lane & 31, hi = lane >> 5;
  const int qg = wave >> 1, kg = wave & 1;
  const int id = blockIdx.x;
  const int j = id >> 3;
  const int bh = ((id & 7) << 2) | (j & 3);
  const int q0 = (j >> 2) << 7;

  const __bf16* Qb = Q + (size_t)bh * (2048 * 64);
  const __bf16* Kp = K + (size_t)bh * 131072;   // K'' chunk layout
  const __bf16* Vp = Vt + (size_t)bh * 131072;  // V'' chunk layout

  __shared__ float Ored[4][32][64];  // 32KB
  __shared__ float Lred[512];        // 2KB

  bf16x8 qf[4];
  {
    const __bf16* qp = Qb + (size_t)(q0 + qg * 32 + l31) * 64 + hi * 8;
#pragma unroll
    for (int i = 0; i < 4; i++) qf[i] = *(const bf16x8*)(qp + i * 16);
  }

  // kf[i] (tile kt) = K[kt+kg*32+l31][(2i+hi)*8 + 0..7]
  //   = Kp + kt*64 + kg*2048 + (2i+hi)*256 + l31*8
  const __bf16* kfr = Kp + kg * 2048 + hi * 256 + l31 * 8;
  // vf[dt][ks] (tile kt) = V[kt+(kg*4+ks*2+hi)*8 + 0..7][dt*32+l31]
  //   = Vp + kt*64 + (kg*4+hi)*512 + ks*1024 + dt*256 + l31*8
  const __bf16* vfr = Vp + (kg * 4 + hi) * 512 + l31 * 8;

  f32x4 rs4 = {};
  f32x16 oacc[2] = {};

  auto loadK = [&](bf16x8 (&kf)[4], int kt) {
#pragma unroll
    for (int i = 0; i < 4; i++)
      kf[i] = *(const bf16x8*)(kfr + (size_t)kt * 64 + i * 512);
  };
  auto loadV = [&](bf16x8 (&vf)[2][2], int kt) {
#pragma unroll
    for (int dt = 0; dt < 2; dt++)
#pragma unroll
      for (int ks = 0; ks < 2; ks++)
        vf[dt][ks] =
            *(const bf16x8*)(vfr + (size_t)kt * 64 + ks * 1024 + dt * 256);
  };

  auto compute = [&](const bf16x8 (&kf)[4], const bf16x8 (&vf)[2][2]) {
    f32x16 s = {};
#pragma unroll
    for (int i = 0; i < 4; i++) s = MFMA32(kf[i], qf[i], s);
    float pe[16];
#pragma unroll
    for (int r = 0; r < 16; r++) pe[r] = __builtin_amdgcn_exp2f(s[r]);
#pragma unroll
    for (int r = 0; r < 16; r++) rs4[r & 3] += pe[r];
    bf16x8 pa[2];
#pragma unroll
    for (int sl = 0; sl < 2; sl++) {
      unsigned wa, wb, wc, wd;
      asm("v_cvt_pk_bf16_f32 %0, %1, %2" : "=v"(wa) : "v"(pe[8 * sl + 0]), "v"(pe[8 * sl + 1]));
      asm("v_cvt_pk_bf16_f32 %0, %1, %2" : "=v"(wb) : "v"(pe[8 * sl + 4]), "v"(pe[8 * sl + 5]));
      asm("v_cvt_pk_bf16_f32 %0, %1, %2" : "=v"(wc) : "v"(pe[8 * sl + 2]), "v"(pe[8 * sl + 3]));
      asm("v_cvt_pk_bf16_f32 %0, %1, %2" : "=v"(wd) : "v"(pe[8 * sl + 6]), "v"(pe[8 * sl + 7]));
      asm("v_permlane32_swap_b32 %0, %1" : "+v"(wa), "+v"(wb));
      asm("v_permlane32_swap_b32 %0, %1" : "+v"(wc), "+v"(wd));
      u32x4v t;
      t[0] = wa; t[1] = wc; t[2] = wb; t[3] = wd;
      pa[sl] = __builtin_bit_cast(bf16x8, t);
    }
#pragma unroll
    for (int dt = 0; dt < 2; dt++)
#pragma unroll
      for (int ks = 0; ks < 2; ks++)
        oacc[dt] = MFMA32(pa[ks], vf[dt][ks], oacc[dt]);
  };

  bf16x8 kfA[4], vfA[2][2], kfB[4], vfB[2][2];
  loadK(kfA, 0);
  loadV(vfA, 0);
#pragma unroll 1
  for (int kt = 0; kt < 2048; kt += 128) {
    loadK(kfB, kt + 64);
    loadV(vfB, kt + 64);
    compute(kfA, vfA);
    if (kt + 128 < 2048) {
      loadK(kfA, kt + 128);
      loadV(vfA, kt + 128);
    }
    compute(kfB, vfB);
  }

  // ---- cross-kg reduction through LDS (only sync point) ----
  float lw = (rs4[0] + rs4[1]) + (rs4[2] + rs4[3]);
  lw += __shfl_xor(lw, 32, 64);
  Lred[wave * 64 + lane] = lw;
  if (kg == 1) {
#pragma unroll
    for (int dt = 0; dt < 2; dt++)
#pragma unroll
      for (int r = 0; r < 16; r++)
        Ored[qg][dt * 16 + r][lane] = oacc[dt][r];
  }
  __syncthreads();
  if (kg == 0) {
    const int b = bh >> 4, h = bh & 15;
#pragma unroll
    for (int r = 0; r < 16; r++) {
      const int qrow = (r & 3) + 8 * (r >> 2) + 4 * hi;
      const float lt =
          Lred[(qg * 2) * 64 + qrow] + Lred[(qg * 2 + 1) * 64 + qrow];
      const float inv = 1.f / lt;
      const int qAbs = q0 + qg * 32 + qrow;
#pragma unroll
      for (int dt = 0; dt < 2; dt++) {
        const float o = oacc[dt][r] + Ored[qg][dt * 16 + r][lane];
        Aout[((size_t)(b * 2048 + qAbs)) * 1024 + h * 64 + dt * 32 + l31] =
            (__bf16)(o * inv);
      }
    }
  }
}

extern "C" void kernel_launch(void* const* d_in, const int* in_sizes, int n_in,
                              void* d_out, int out_size, void* d_ws, size_t ws_size,
                              hipStream_t stream) {
  const float* x   = (const float*)d_in[0];
  const float* ctx = (const float*)d_in[1];
  const float* Wq  = (const float*)d_in[2];
  const float* Wv  = (const float*)d_in[3];
  const float* Wo  = (const float*)d_in[4];
  const float* bo  = (const float*)d_in[5];

  char* ws = (char*)d_ws;
  const size_t MB = 1024 * 1024;
  __bf16* xb   = (__bf16*)(ws + 0 * MB);   // [4096,1024]; contiguous with cb
  __bf16* cb   = (__bf16*)(ws + 8 * MB);   // [4096,1024]
  __bf16* Wqb  = (__bf16*)(ws + 16 * MB);  // contiguous with Wvb
  __bf16* Wvb  = (__bf16*)(ws + 18 * MB);
  __bf16* Wob  = (__bf16*)(ws + 20 * MB);
  __bf16* qh   = (__bf16*)(ws + 22 * MB);  // [b,h,s,d], pre-scaled by 0.18034
  __bf16* kh   = (__bf16*)(ws + 30 * MB);  // K'' chunk layout [bh][s/32][d/8][32][8]
  __bf16* vt   = (__bf16*)(ws + 38 * MB);  // V'' chunk layout [bh][s/8][d][8]
  __bf16* attn = xb;  // xb dead after QK projection

  cvt_all_kernel<<<5632, 256, 0, stream>>>(x, ctx, Wq, Wv, Wo, xb, cb, Wqb, Wvb, Wob);

  gemm_proj<<<192, 512, 0, stream>>>(xb, Wqb, (void*)qh, (void*)kh, (void*)vt);

  attn_kernel<<<512, 512, 0, stream>>>(qh, kh, vt, attn);

  gemm_out<<<512, 256, 0, stream>>>(attn, Wob, (float*)d_out, bo);
}